// Round 1
// baseline (43.768 us; speedup 1.0000x reference)
//
#include <hip/hip_runtime.h>

// Problem constants (from the reference): CNO=10000, PAD=10001, KS=10003.
#define CNO_C 10000
#define PAD_C 10001
#define KS_C  10003

// One thread per (query q, offset j). For MR64=true, mr==64 so q = tid>>6 and
// the whole 64-lane wave works on one query: per-query loads are wave-uniform
// (broadcast), order-gather and stores are coalesced 256B/wave.
template <bool MR64>
__global__ __launch_bounds__(256) void akfi_kernel(
    const int* __restrict__ qa,                                   // B x 3
    const int* __restrict__ o0, const int* __restrict__ s0, const int* __restrict__ l0,
    const int* __restrict__ o1, const int* __restrict__ s1, const int* __restrict__ l1,
    const int* __restrict__ op, const int* __restrict__ sp, const int* __restrict__ lp,
    int n0, int n1, int npred,                                    // starts[] sizes
    int F, int B, int mr,
    int* __restrict__ out_idx,                                    // B x mr
    int* __restrict__ out_valid)                                  // B x mr (0/1)
{
    long long t = (long long)blockIdx.x * blockDim.x + threadIdx.x;
    long long total = (long long)B * (long long)mr;
    if (t >= total) return;

    int q, j;
    if (MR64) { q = (int)(t >> 6); j = (int)(t & 63); }
    else      { q = (int)(t / mr); j = (int)(t % mr); }

    // Wave-uniform query row (all lanes same q when MR64).
    int p  = qa[q * 3 + 0];
    int a0 = qa[q * 3 + 1];
    int a1 = qa[q * 3 + 2];

    bool is_c0 = (a0 <= CNO_C) && (a0 != PAD_C);
    bool is_c1 = (a1 <= CNO_C) && (a1 != PAD_C);
    bool both  = (!is_c0) && (!is_c1) && (p != PAD_C);

    // Selection per reference: both_var overrides, else use0 picks fi0, else fi1.
    // Equivalent (both requires !is_c0): if is_c0 -> t0; elif both -> tp; else -> t1.
    const int* order;
    const int* starts;
    const int* lens;
    int key, nsz;
    bool isc;
    if (is_c0)      { order = o0; starts = s0; lens = l0; key = p * KS_C + a0; nsz = n0;    isc = true;  }
    else if (both)  { order = op; starts = sp; lens = lp; key = p;             nsz = npred; isc = true;  }
    else            { order = o1; starts = s1; lens = l1; key = p * KS_C + a1; nsz = n1;    isc = is_c1; }

    int safe = key;
    if (safe < 0)       safe = 0;
    if (safe > nsz - 1) safe = nsz - 1;

    int left = starts[safe];                  // wave-uniform
    int cnt  = lens[safe];                    // wave-uniform
    if (cnt > mr) cnt = mr;

    int idx = left + j;                       // reference clamps to [0, F-1]
    if (idx > F - 1) idx = F - 1;
    if (idx < 0)     idx = 0;

    int fact = order[idx];                    // coalesced 256B per wave
    int v    = ((j < cnt) && isc) ? 1 : 0;

    long long ob = (long long)q * mr + j;
    out_idx[ob]   = fact;
    out_valid[ob] = v;
}

extern "C" void kernel_launch(void* const* d_in, const int* in_sizes, int n_in,
                              void* d_out, int out_size, void* d_ws, size_t ws_size,
                              hipStream_t stream) {
    const int* qa = (const int*)d_in[0];
    const int* o0 = (const int*)d_in[1];
    const int* s0 = (const int*)d_in[2];
    const int* l0 = (const int*)d_in[3];
    const int* o1 = (const int*)d_in[4];
    const int* s1 = (const int*)d_in[5];
    const int* l1 = (const int*)d_in[6];
    const int* op = (const int*)d_in[7];
    const int* sp = (const int*)d_in[8];
    const int* lp = (const int*)d_in[9];
    // d_in[10] is max_results (device scalar) — derive mr on host instead:
    // out = (fact_idx[B*mr], valid[B*mr]) concatenated as int32.
    int B  = in_sizes[0] / 3;
    int F  = in_sizes[1];
    int n0 = in_sizes[2];
    int n1 = in_sizes[5];
    int npred = in_sizes[8];
    int mr = out_size / (2 * B);

    int* out_idx   = (int*)d_out;
    int* out_valid = (int*)d_out + (long long)B * mr;

    long long total = (long long)B * (long long)mr;
    int block = 256;
    int blocks = (int)((total + block - 1) / block);

    if (mr == 64) {
        akfi_kernel<true><<<blocks, block, 0, stream>>>(
            qa, o0, s0, l0, o1, s1, l1, op, sp, lp,
            n0, n1, npred, F, B, mr, out_idx, out_valid);
    } else {
        akfi_kernel<false><<<blocks, block, 0, stream>>>(
            qa, o0, s0, l0, o1, s1, l1, op, sp, lp,
            n0, n1, npred, F, B, mr, out_idx, out_valid);
    }
}

// Round 2
// 31.766 us; speedup vs baseline: 1.3778x; 1.3778x over previous
//
#include <hip/hip_runtime.h>

// Problem constants (from the reference): CNO=10000, PAD=10001, KS=10003.
#define CNO_C 10000
#define PAD_C 10001
#define KS_C  10003

// Vectorized: one thread per (query q, 4 consecutive offsets j4..j4+3).
// For mr=64: 16 threads per query; stores are 16B-aligned int4; the order
// gather is 4 consecutive dwords -> SLP-vectorized to global_load_dwordx4
// in the (vast-majority) fully-in-bounds case.
template <bool MR64>
__global__ __launch_bounds__(256) void akfi_vec4(
    const int* __restrict__ qa,                                   // B x 3
    const int* __restrict__ o0, const int* __restrict__ s0, const int* __restrict__ l0,
    const int* __restrict__ o1, const int* __restrict__ s1, const int* __restrict__ l1,
    const int* __restrict__ op, const int* __restrict__ sp, const int* __restrict__ lp,
    int n0, int n1, int npred,                                    // starts[] sizes
    int F, int B, int mr,
    int* __restrict__ out_idx,                                    // B x mr
    int* __restrict__ out_valid)                                  // B x mr (0/1)
{
    long long t = (long long)blockIdx.x * blockDim.x + threadIdx.x;
    int per_q = mr >> 2;                      // threads per query
    long long total = (long long)B * per_q;
    if (t >= total) return;

    int q, j4;
    if (MR64) { q = (int)(t >> 4); j4 = (int)((t & 15) << 2); }
    else      { q = (int)(t / per_q); j4 = (int)(t % per_q) << 2; }

    int p  = qa[q * 3 + 0];
    int a0 = qa[q * 3 + 1];
    int a1 = qa[q * 3 + 2];

    bool is_c0 = (a0 <= CNO_C) && (a0 != PAD_C);
    bool is_c1 = (a1 <= CNO_C) && (a1 != PAD_C);
    bool both  = (!is_c0) && (!is_c1) && (p != PAD_C);

    // Reference select order: is_c0 -> table0; elif both_var -> pred table; else table1.
    const int* order;
    const int* starts;
    const int* lens;
    int key, nsz;
    bool isc;
    if (is_c0)      { order = o0; starts = s0; lens = l0; key = p * KS_C + a0; nsz = n0;    isc = true;  }
    else if (both)  { order = op; starts = sp; lens = lp; key = p;             nsz = npred; isc = true;  }
    else            { order = o1; starts = s1; lens = l1; key = p * KS_C + a1; nsz = n1;    isc = is_c1; }

    int safe = key;
    if (safe < 0)       safe = 0;
    if (safe > nsz - 1) safe = nsz - 1;

    int left = starts[safe];
    int cnt  = lens[safe];
    if (cnt > mr) cnt = mr;

    int idx0 = left + j4;                     // reference clamps each to [0, F-1]
    int f0, f1, f2, f3;
    if (idx0 >= 0 && idx0 + 3 <= F - 1) {
        // contiguous, in-bounds: compiler vectorizes to dwordx4
        f0 = order[idx0];
        f1 = order[idx0 + 1];
        f2 = order[idx0 + 2];
        f3 = order[idx0 + 3];
    } else {
        int i0 = min(max(idx0,     0), F - 1);
        int i1 = min(max(idx0 + 1, 0), F - 1);
        int i2 = min(max(idx0 + 2, 0), F - 1);
        int i3 = min(max(idx0 + 3, 0), F - 1);
        f0 = order[i0]; f1 = order[i1]; f2 = order[i2]; f3 = order[i3];
    }

    int4 fv = make_int4(f0, f1, f2, f3);
    int4 vv = make_int4(
        (isc && (j4     < cnt)) ? 1 : 0,
        (isc && (j4 + 1 < cnt)) ? 1 : 0,
        (isc && (j4 + 2 < cnt)) ? 1 : 0,
        (isc && (j4 + 3 < cnt)) ? 1 : 0);

    long long ob = (long long)q * mr + j4;    // 16B-aligned (j4 multiple of 4)
    *reinterpret_cast<int4*>(out_idx + ob)   = fv;
    *reinterpret_cast<int4*>(out_valid + ob) = vv;
}

// Fallback scalar kernel for mr not divisible by 4.
__global__ __launch_bounds__(256) void akfi_scalar(
    const int* __restrict__ qa,
    const int* __restrict__ o0, const int* __restrict__ s0, const int* __restrict__ l0,
    const int* __restrict__ o1, const int* __restrict__ s1, const int* __restrict__ l1,
    const int* __restrict__ op, const int* __restrict__ sp, const int* __restrict__ lp,
    int n0, int n1, int npred,
    int F, int B, int mr,
    int* __restrict__ out_idx,
    int* __restrict__ out_valid)
{
    long long t = (long long)blockIdx.x * blockDim.x + threadIdx.x;
    long long total = (long long)B * (long long)mr;
    if (t >= total) return;
    int q = (int)(t / mr), j = (int)(t % mr);

    int p  = qa[q * 3 + 0];
    int a0 = qa[q * 3 + 1];
    int a1 = qa[q * 3 + 2];
    bool is_c0 = (a0 <= CNO_C) && (a0 != PAD_C);
    bool is_c1 = (a1 <= CNO_C) && (a1 != PAD_C);
    bool both  = (!is_c0) && (!is_c1) && (p != PAD_C);

    const int* order; const int* starts; const int* lens;
    int key, nsz; bool isc;
    if (is_c0)      { order = o0; starts = s0; lens = l0; key = p * KS_C + a0; nsz = n0;    isc = true;  }
    else if (both)  { order = op; starts = sp; lens = lp; key = p;             nsz = npred; isc = true;  }
    else            { order = o1; starts = s1; lens = l1; key = p * KS_C + a1; nsz = n1;    isc = is_c1; }

    int safe = min(max(key, 0), nsz - 1);
    int left = starts[safe];
    int cnt  = min(lens[safe], mr);
    int idx  = min(max(left + j, 0), F - 1);

    long long ob = (long long)q * mr + j;
    out_idx[ob]   = order[idx];
    out_valid[ob] = (isc && j < cnt) ? 1 : 0;
}

extern "C" void kernel_launch(void* const* d_in, const int* in_sizes, int n_in,
                              void* d_out, int out_size, void* d_ws, size_t ws_size,
                              hipStream_t stream) {
    const int* qa = (const int*)d_in[0];
    const int* o0 = (const int*)d_in[1];
    const int* s0 = (const int*)d_in[2];
    const int* l0 = (const int*)d_in[3];
    const int* o1 = (const int*)d_in[4];
    const int* s1 = (const int*)d_in[5];
    const int* l1 = (const int*)d_in[6];
    const int* op = (const int*)d_in[7];
    const int* sp = (const int*)d_in[8];
    const int* lp = (const int*)d_in[9];
    int B  = in_sizes[0] / 3;
    int F  = in_sizes[1];
    int n0 = in_sizes[2];
    int n1 = in_sizes[5];
    int npred = in_sizes[8];
    int mr = out_size / (2 * B);

    int* out_idx   = (int*)d_out;
    int* out_valid = (int*)d_out + (long long)B * mr;

    int block = 256;
    if ((mr & 3) == 0) {
        long long total = (long long)B * (mr >> 2);
        int blocks = (int)((total + block - 1) / block);
        if (mr == 64) {
            akfi_vec4<true><<<blocks, block, 0, stream>>>(
                qa, o0, s0, l0, o1, s1, l1, op, sp, lp,
                n0, n1, npred, F, B, mr, out_idx, out_valid);
        } else {
            akfi_vec4<false><<<blocks, block, 0, stream>>>(
                qa, o0, s0, l0, o1, s1, l1, op, sp, lp,
                n0, n1, npred, F, B, mr, out_idx, out_valid);
        }
    } else {
        long long total = (long long)B * (long long)mr;
        int blocks = (int)((total + block - 1) / block);
        akfi_scalar<<<blocks, block, 0, stream>>>(
            qa, o0, s0, l0, o1, s1, l1, op, sp, lp,
            n0, n1, npred, F, B, mr, out_idx, out_valid);
    }
}